// Round 3
// baseline (211.363 us; speedup 1.0000x reference)
//
#include <hip/hip_runtime.h>
#include <cstdint>

#define BTOT 4096
#define NBLK 1366   // ceil(4096/3)

typedef float f32x2 __attribute__((ext_vector_type(2)));

// One wave per block. Lanes 0..59 = 3 batch groups x 20 neurons; lanes 60..63 idle dups.
// LDS: only LUT[4][32][20] (nibble-sums of W2 columns, pre-scaled by 0.5) + 64 floats
// for the epilogue accumulator exchange. x is loaded global->VGPR (group-uniform
// addresses coalesce to 3 x 16B segments; x is L3-resident on timed replays).
__global__ __launch_bounds__(64, 2)
void snn_kernel(const float* __restrict__ x, const float* __restrict__ W1,
                const float* __restrict__ W2, const float* __restrict__ W3,
                float* __restrict__ out) {
  __shared__ __align__(16) float lutf[2560 + 64];
  const int lane = threadIdx.x;
  const int bid  = blockIdx.x;

  // Build LUT: lutf[q*640 + m*20 + i] = 0.5 * sum_{k: m has bit k} W2[i][5*q+k]
  for (int idx = lane; idx < 2560; idx += 64) {
    int q   = idx / 640;
    int rem = idx - q * 640;
    int m   = rem / 20;
    int i   = rem - m * 20;
    float s = 0.f;
    #pragma unroll
    for (int k = 0; k < 5; ++k)
      if (m & (1 << k)) s += W2[i * 20 + q * 5 + k];
    lutf[idx] = 0.5f * s;
  }

  const int  g3     = lane / 20;            // 0..3
  const int  g      = g3 < 3 ? g3 : 2;      // clamp idle lanes onto group 2
  const int  i      = lane - g * 20;        // 0..19 (20..23 for idle lanes)
  const int  i19    = i < 20 ? i : 19;
  const bool active = (g3 < 3);
  const long b      = (long)bid * 3 + g;
  const bool bvalid = (b < BTOT);
  const long bc     = bvalid ? b : (BTOT - 1);   // clamp OOB batch for loads

  // W1 row, pre-scaled by 0.5, splatted for packed FMA over dt-pairs.
  f32x2 wsp[14];
  #pragma unroll
  for (int l = 0; l < 14; ++l) {
    float w = 0.5f * W1[i19 * 14 + l];
    wsp[l] = (f32x2){w, w};
  }

  float v1 = 0.f, v2 = 0.f, aacc = 0.f;
  const unsigned sh = 20u * (unsigned)g;

  // Row l of this group's batch starts at float4 index l*250 (1000 t-samples/row).
  const float4* __restrict__ xr0 = (const float4*)(x + bc * 14000);

  __syncthreads();  // LUT ready

  float4 xa[14], xb[14];
  #pragma unroll
  for (int l = 0; l < 14; ++l) xa[l] = xr0[l * 250];

  auto step4 = [&](const float4 (&xr)[14]) {
    // ---- Phase A: h1 (packed over dt pairs) + v1 chain + ballots ----
    f32x2 h01 = {0.f, 0.f}, h23 = {0.f, 0.f};
    #pragma unroll
    for (int l = 0; l < 14; ++l) {
      h01 = __builtin_elementwise_fma(wsp[l], (f32x2){xr[l].x, xr[l].y}, h01);
      h23 = __builtin_elementwise_fma(wsp[l], (f32x2){xr[l].z, xr[l].w}, h23);
    }
    float h1v[4] = {h01.x, h01.y, h23.x, h23.y};

    unsigned mk[4];
    #pragma unroll
    for (int dt = 0; dt < 4; ++dt) {
      v1 = fmaf(v1, 0.5f, h1v[dt]);   // v' = v/2 + h/2 (W1 pre-scaled)
      const bool sp1 = (v1 >= 5.0f);
      v1 = sp1 ? 0.f : v1;
      mk[dt] = (unsigned)(__ballot(sp1) >> sh);  // bits >19 junk; bfe masks below
    }

    // ---- Phase B: all 16 LUT loads issued back-to-back ----
    float hq[16];
    #pragma unroll
    for (int dt = 0; dt < 4; ++dt) {
      #pragma unroll
      for (int q = 0; q < 4; ++q)
        hq[dt * 4 + q] = lutf[q * 640 + ((mk[dt] >> (5 * q)) & 31u) * 20 + i19];
    }

    // ---- Phase C: v2 / aacc chain ----
    #pragma unroll
    for (int dt = 0; dt < 4; ++dt) {
      const float h2 = (hq[dt * 4 + 0] + hq[dt * 4 + 1]) +
                       (hq[dt * 4 + 2] + hq[dt * 4 + 3]);  // already *0.5
      v2 = fmaf(v2, 0.5f, h2);
      const bool sp2 = (v2 >= 5.0f);
      v2 = sp2 ? 0.f : v2;
      aacc = fmaf(aacc, 0.5f, sp2 ? 0.5f : 0.f);
    }
  };

  // Unroll-2 ping-pong: prefetch next 4 timesteps into the other reg buffer
  // while computing the current one (static indexing only).
  for (int t4 = 0; t4 < 250; t4 += 2) {
    #pragma unroll
    for (int l = 0; l < 14; ++l) xb[l] = xr0[l * 250 + t4 + 1];
    step4(xa);
    if (t4 + 2 < 250) {
      #pragma unroll
      for (int l = 0; l < 14; ++l) xa[l] = xr0[l * 250 + t4 + 2];
    }
    step4(xb);
  }

  // Epilogue: out[b][k] = exp( sum_j W3[k][j] * a[j] )
  __syncthreads();
  if (active) lutf[2560 + g * 20 + i] = aacc;
  __syncthreads();
  if (active && bvalid) {
    float ar[20];
    #pragma unroll
    for (int j = 0; j < 20; ++j) ar[j] = lutf[2560 + g * 20 + j];
    for (int q = 0; q < 25; ++q) {
      const int k = i + 20 * q;
      float acc = 0.f;
      #pragma unroll
      for (int j = 0; j < 20; ++j) acc = fmaf(W3[k * 20 + j], ar[j], acc);
      out[b * 500 + k] = expf(acc);
    }
  }
}

extern "C" void kernel_launch(void* const* d_in, const int* in_sizes, int n_in,
                              void* d_out, int out_size, void* d_ws, size_t ws_size,
                              hipStream_t stream) {
  const float* x  = (const float*)d_in[0];
  const float* W1 = (const float*)d_in[1];
  const float* W2 = (const float*)d_in[2];
  const float* W3 = (const float*)d_in[3];
  float* out = (float*)d_out;
  snn_kernel<<<dim3(NBLK), dim3(64), 0, stream>>>(x, W1, W2, W3, out);
}